// Round 1
// baseline (213.156 us; speedup 1.0000x reference)
//
#include <hip/hip_runtime.h>

#define N 8
#define L 6400
#define C 256
#define K 100
#define CHUNKS 32
#define ROWS (L / CHUNKS)   // 200

// ---------------- kernel 0: zero the fp64 accumulators in ws ----------------
__global__ void k0_init(double* __restrict__ A) {
    int t = blockIdx.x * blockDim.x + threadIdx.x;
    if (t < 2 * N * K) A[t] = 0.0;
}

// ---------------- kernel 1: A[n][half][k] = sum_l prob[n, half*L + l, k] ----
// block = 256 threads: two rows per iteration, lanes kk<100 active.
// fp64 accumulation so the argmax matches the (f64) numpy reference.
__global__ void k1_accum(const float* __restrict__ prob, double* __restrict__ A) {
    int b     = blockIdx.x;
    int chunk = b & (CHUNKS - 1);
    int half  = (b >> 5) & 1;
    int n     = b >> 6;
    int t     = threadIdx.x;
    int sub   = t >> 7;      // which of 2 rows per iteration
    int kk    = t & 127;
    const float* base = prob + ((size_t)(n * 2 + half) * L + (size_t)chunk * ROWS) * K;
    if (kk < K) {
        double acc = 0.0;
        for (int j = sub; j < ROWS; j += 2)
            acc += (double)base[(size_t)j * K + kk];
        atomicAdd(&A[(n * 2 + half) * K + kk], acc);
    }
}

// ---------------- kernel 2: kstar[n] = argmax_k A0[n][k]*A1[n][k] -----------
// strict '>' keeps the FIRST max -> matches top_k lowest-index tie-break.
__global__ void k2_argmax(const double* __restrict__ A, int* __restrict__ kstar) {
    int n = threadIdx.x;
    if (n < N) {
        const double* a0 = A + (size_t)(n * 2) * K;
        const double* a1 = A + (size_t)(n * 2 + 1) * K;
        double best = -1.0;
        int bi = 0;
        for (int k = 0; k < K; ++k) {
            double v = a0[k] * a1[k];
            if (v > best) { best = v; bi = k; }
        }
        kstar[n] = bi;
    }
}

// ---------------- kernel 3: maskbuf[n*L+l] = topics[n, l, kstar[n]] > 0.5 ---
__global__ void k3_extract(const float* __restrict__ topics,
                           const int* __restrict__ kstar,
                           int* __restrict__ maskbuf) {
    int idx = blockIdx.x * 256 + threadIdx.x;   // < N*L
    int n = idx / L;
    int l = idx - n * L;
    int k = kstar[n];
    float v = topics[((size_t)n * 2 * L + (size_t)l) * K + (size_t)k];
    maskbuf[idx] = (v > 0.5f) ? 1 : 0;
}

// ---------------- kernel 4: per-n exclusive scan -> destbuf, lenbuf ---------
// one block per n; all 25 chunk loads issued up-front (independent), then
// ballot/popcount wave scan + LDS wave-offset combine.
__global__ void k4_scan(const int* __restrict__ maskbuf,
                        int* __restrict__ destbuf,
                        int* __restrict__ lenbuf) {
    int n    = blockIdx.x;
    int t    = threadIdx.x;
    int lane = t & 63;
    int wave = t >> 6;
    __shared__ int wsum[4];
    int mv[25];
#pragma unroll
    for (int c = 0; c < 25; ++c)
        mv[c] = maskbuf[n * L + c * 256 + t];

    int running = 0;
#pragma unroll
    for (int c = 0; c < 25; ++c) {
        int m = mv[c];
        unsigned long long bal = __ballot(m != 0);
        int rank_in_wave = __popcll(bal & ((1ull << lane) - 1ull));
        int wtot = __popcll(bal);
        if (lane == 0) wsum[wave] = wtot;
        __syncthreads();
        int woff = 0, tot = 0;
#pragma unroll
        for (int w = 0; w < 4; ++w) {
            int s = wsum[w];
            if (w < wave) woff += s;
            tot += s;
        }
        destbuf[n * L + c * 256 + t] = m ? (running + woff + rank_in_wave) : -1;
        running += tot;
        __syncthreads();
    }
    if (t == 0) lenbuf[n] = running;
}

// ---------------- kernel 5: scatter selected rows + zero-fill + new_mask ----
// one wave per row r = n*L + l (C=256 floats = 64 lanes * float4).
__global__ void k5_out(const float* __restrict__ feat,
                       const int* __restrict__ destbuf,
                       const int* __restrict__ lenbuf,
                       float* __restrict__ out) {
    int r    = blockIdx.x * 4 + (threadIdx.x >> 6);
    int lane = threadIdx.x & 63;
    int n = r / L;
    int l = r - n * L;
    int d   = destbuf[r];
    int len = lenbuf[n];
    const float4* feat4 = (const float4*)feat;
    float4*       out4  = (float4*)out;
    if (d >= 0) {
        float4 v = feat4[(size_t)r * 64 + lane];
        out4[((size_t)n * L + (size_t)d) * 64 + lane] = v;
    }
    if (l >= len) {
        out4[(size_t)r * 64 + lane] = make_float4(0.f, 0.f, 0.f, 0.f);
    }
    if (lane == 0)
        out[(size_t)N * L * C + (size_t)r] = (l < len) ? 1.0f : 0.0f;
}

extern "C" void kernel_launch(void* const* d_in, const int* in_sizes, int n_in,
                              void* d_out, int out_size, void* d_ws, size_t ws_size,
                              hipStream_t stream) {
    const float* feat   = (const float*)d_in[0];
    const float* prob   = (const float*)d_in[1];
    const float* topics = (const float*)d_in[2];
    // d_in[3] = n_samples: only the top-1 index is ever used by the reference.

    // workspace layout (poisoned 0xAA every call -> k0 zeroes what needs it)
    double* A       = (double*)d_ws;          // 2*N*K = 1600 doubles
    int*    kstar   = (int*)(A + 2 * N * K);  // N
    int*    lenbuf  = kstar + N;              // N
    int*    maskbuf = lenbuf + N;             // N*L
    int*    destbuf = maskbuf + N * L;        // N*L   (total ~423 KB)

    float* out = (float*)d_out;

    k0_init   <<<7, 256, 0, stream>>>(A);
    k1_accum  <<<N * 2 * CHUNKS, 256, 0, stream>>>(prob, A);
    k2_argmax <<<1, 64, 0, stream>>>(A, kstar);
    k3_extract<<<(N * L) / 256, 256, 0, stream>>>(topics, kstar, maskbuf);
    k4_scan   <<<N, 256, 0, stream>>>(maskbuf, destbuf, lenbuf);
    k5_out    <<<(N * L) / 4, 256, 0, stream>>>(feat, destbuf, lenbuf, out);
}

// Round 2
// 170.387 us; speedup vs baseline: 1.2510x; 1.2510x over previous
//
#include <hip/hip_runtime.h>

#define N 8
#define L 6400
#define C 256
#define K 100
#define CPS 32              // chunks per (n,half) segment
#define RPC (L / CPS)       // 200 rows per chunk

// ---- kA: per-chunk column sums. P[b][k] (fp64), b = seg*CPS + chunk --------
// 256 threads: group g = t&31 (g<25 active) owns columns 4g..4g+3 of row
// r = i*8 + (t>>5). Loads are contiguous float4 per row, fully unrolled.
__global__ void kA_partial(const float* __restrict__ prob, double* __restrict__ P) {
    int b = blockIdx.x;                 // 0..511
    int seg = b >> 5, chunk = b & 31;
    int t = threadIdx.x;
    int r8 = t >> 5, g = t & 31;
    const float4* base = (const float4*)prob
        + (size_t)seg * (L * 25) + (size_t)chunk * (RPC * 25);
    double a0 = 0, a1 = 0, a2 = 0, a3 = 0;
    if (g < 25) {
#pragma unroll
        for (int i = 0; i < RPC / 8; ++i) {       // 25 iters
            float4 v = base[(i * 8 + r8) * 25 + g];
            a0 += v.x; a1 += v.y; a2 += v.z; a3 += v.w;
        }
    }
    __shared__ double sdata[8][100];
    if (g < 25) {
        int k4 = g * 4;
        sdata[r8][k4] = a0; sdata[r8][k4 + 1] = a1;
        sdata[r8][k4 + 2] = a2; sdata[r8][k4 + 3] = a3;
    }
    __syncthreads();
    if (t < 100) {
        double s = 0;
#pragma unroll
        for (int r = 0; r < 8; ++r) s += sdata[r][t];
        P[b * 100 + t] = s;
    }
}

// ---- kB: per-n combine chunks + argmax (strict '>' = first-max tie-break) --
__global__ void kB_argmax(const double* __restrict__ P, int* __restrict__ kstar) {
    int n = blockIdx.x, t = threadIdx.x;      // 128 threads
    __shared__ double vbuf[100];
    if (t < 100) {
        const double* p0 = P + (size_t)(2 * n) * CPS * 100 + t;
        const double* p1 = P + (size_t)(2 * n + 1) * CPS * 100 + t;
        double s0 = 0, s1 = 0;
#pragma unroll 8
        for (int c = 0; c < CPS; ++c) { s0 += p0[c * 100]; s1 += p1[c * 100]; }
        vbuf[t] = s0 * s1;
    }
    __syncthreads();
    if (t == 0) {
        double best = -1.0; int bi = 0;
        for (int k = 0; k < K; ++k) {
            double v = vbuf[k];
            if (v > best) { best = v; bi = k; }
        }
        kstar[n] = bi;
    }
}

// ---- kC: gather topic column -> ballot bitmask (u64 per 64 rows) -----------
__global__ void kC_bits(const float* __restrict__ topics,
                        const int* __restrict__ kstar,
                        unsigned long long* __restrict__ bits) {
    int idx = blockIdx.x * 256 + threadIdx.x;     // < N*L (n*L divisible by 64)
    int n = idx / L;
    int l = idx - n * L;
    int k = kstar[n];
    float v = topics[((size_t)n * 2 * L + (size_t)l) * K + (size_t)k];
    unsigned long long bal = __ballot(v > 0.5f);
    if ((threadIdx.x & 63) == 0) bits[idx >> 6] = bal;
}

// ---- kD: per-n word-prefix offsets + len + coalesced new_mask write --------
__global__ void kD_scan(const unsigned long long* __restrict__ bits,
                        int* __restrict__ woffs, int* __restrict__ lenbuf,
                        float* __restrict__ out) {
    int n = blockIdx.x, t = threadIdx.x;      // 128 threads
    __shared__ int cnts[100];
    __shared__ int len_s;
    if (t < 100) cnts[t] = __popcll(bits[n * 100 + t]);
    __syncthreads();
    if (t < 100) {
        int s = 0;
        for (int w = 0; w < t; ++w) s += cnts[w];
        woffs[n * 100 + t] = s;
    }
    if (t == 0) {
        int s = 0;
        for (int w = 0; w < 100; ++w) s += cnts[w];
        lenbuf[n] = s; len_s = s;
    }
    __syncthreads();
    int len = len_s;
    float* om = out + (size_t)N * L * C + (size_t)n * L;
    for (int idx = t; idx < L; idx += 128) om[idx] = (idx < len) ? 1.0f : 0.0f;
}

// ---- kE: one wave per row: scatter selected feat rows + zero-fill ----------
__global__ void __launch_bounds__(256)
kE_out(const float* __restrict__ feat,
       const unsigned long long* __restrict__ bits,
       const int* __restrict__ woffs, const int* __restrict__ lenbuf,
       float* __restrict__ out) {
    int r = blockIdx.x * 4 + (threadIdx.x >> 6);
    int lane = threadIdx.x & 63;
    int n = r / L;
    int l = r - n * L;
    unsigned long long word = bits[r >> 6];
    int len = lenbuf[n];
    const float4* f4 = (const float4*)feat;
    float4* o4 = (float4*)out;
    int bpos = l & 63;
    if ((word >> bpos) & 1ull) {
        int d = woffs[n * 100 + (l >> 6)]
              + __popcll(word & ((1ull << bpos) - 1ull));
        float4 v = f4[(size_t)r * 64 + lane];
        o4[((size_t)n * L + (size_t)d) * 64 + lane] = v;
    }
    if (l >= len)
        o4[(size_t)r * 64 + lane] = make_float4(0.f, 0.f, 0.f, 0.f);
}

extern "C" void kernel_launch(void* const* d_in, const int* in_sizes, int n_in,
                              void* d_out, int out_size, void* d_ws, size_t ws_size,
                              hipStream_t stream) {
    const float* feat   = (const float*)d_in[0];
    const float* prob   = (const float*)d_in[1];
    const float* topics = (const float*)d_in[2];

    // ws layout (~420 KB, every slot written before read each call)
    double* P                 = (double*)d_ws;                      // 512*100
    unsigned long long* bits  = (unsigned long long*)(P + 512 * 100); // 800
    int* woffs                = (int*)(bits + 800);                 // 800
    int* kstar                = woffs + 800;                        // 8
    int* lenbuf               = kstar + 8;                          // 8

    float* out = (float*)d_out;

    kA_partial<<<16 * CPS, 256, 0, stream>>>(prob, P);
    kB_argmax <<<N, 128, 0, stream>>>(P, kstar);
    kC_bits   <<<(N * L) / 256, 256, 0, stream>>>(topics, kstar, bits);
    kD_scan   <<<N, 128, 0, stream>>>(bits, woffs, lenbuf, out);
    kE_out    <<<(N * L) / 4, 256, 0, stream>>>(feat, bits, woffs, lenbuf, out);
}